// Round 5
// baseline (2602.186 us; speedup 1.0000x reference)
//
#include <hip/hip_runtime.h>
#include <cstdint>

using half_t = _Float16;
using half8  = __attribute__((ext_vector_type(8))) _Float16;
using half4v = __attribute__((ext_vector_type(4))) _Float16;
using f32x4  = __attribute__((ext_vector_type(4))) float;
using flt4v  = __attribute__((ext_vector_type(4))) float;

namespace {
constexpr int kT = 16, kH = 1024, kFH = 4096, kC = 2513, kCP = 2560;
constexpr int kSlot = 128 * 1024;   // elements per state slot (128 rows x 1024)
constexpr int kPar  = 17 * kSlot;   // elements per parity plane
constexpr unsigned kBlocks = 512;   // 2 blocks/CU x 256 CUs (LDS-capped)
}

__device__ __forceinline__ void gload16(const void* g, void* l) {
  __builtin_amdgcn_global_load_lds((const __attribute__((address_space(1))) void*)g,
                                   (__attribute__((address_space(3))) void*)l, 16, 0, 0);
}
__device__ __forceinline__ float sgm(float x) { return 1.0f / (1.0f + __expf(-x)); }

// device-scope sense-reversal grid barrier (guide G16: device-scope atomics +
// fences; per-XCD L2 non-coherence handled by __threadfence release/acquire)
__device__ __forceinline__ void grid_barrier(unsigned* cnt, unsigned* gen) {
  __syncthreads();
  if (threadIdx.x == 0) {
    __threadfence();  // release my Hbuf/Cbuf/xi writes device-wide
    unsigned g = __hip_atomic_load(gen, __ATOMIC_ACQUIRE, __HIP_MEMORY_SCOPE_AGENT);
    unsigned a = __hip_atomic_fetch_add(cnt, 1u, __ATOMIC_ACQ_REL, __HIP_MEMORY_SCOPE_AGENT) + 1u;
    if (a == kBlocks) {
      __hip_atomic_store(cnt, 0u, __ATOMIC_RELAXED, __HIP_MEMORY_SCOPE_AGENT);
      __hip_atomic_fetch_add(gen, 1u, __ATOMIC_RELEASE, __HIP_MEMORY_SCOPE_AGENT);
    } else {
      while (__hip_atomic_load(gen, __ATOMIC_ACQUIRE, __HIP_MEMORY_SCOPE_AGENT) == g)
        __builtin_amdgcn_s_sleep(2);
    }
    __threadfence();  // acquire: drop stale lines before reading peers' writes
  }
  __syncthreads();
}

// ---------------- fused setup: weight casts + x transpose + bias packs -------
__global__ void setup_all(const flt4v* __restrict__ WiR, const flt4v* __restrict__ WhR,
                          const flt4v* __restrict__ WiU, const flt4v* __restrict__ WhU,
                          const flt4v* __restrict__ Wc, const float* __restrict__ x,
                          const float* __restrict__ biR, const float* __restrict__ bhR,
                          const float* __restrict__ biU, const float* __restrict__ bhU,
                          const float* __restrict__ bc,
                          half4v* __restrict__ WiRh, half4v* __restrict__ WhRh,
                          half4v* __restrict__ WiUh, half4v* __restrict__ WhUh,
                          half4v* __restrict__ Wch, half_t* __restrict__ xh,
                          float* __restrict__ br_p, float* __restrict__ bu_p,
                          float* __restrict__ bcp) {
  int blk = blockIdx.x;
  if (blk < 18944) {  // weight casts, 1024 f32 elements (256 x flt4v) per block
    long i = (long)blk * 256 + threadIdx.x;
    const long Q = 1048576;
    if (i < Q) { WiRh[i] = __builtin_convertvector(WiR[i], half4v); return; }
    i -= Q;
    if (i < Q) { WhRh[i] = __builtin_convertvector(WhR[i], half4v); return; }
    i -= Q;
    if (i < Q) { WiUh[i] = __builtin_convertvector(WiU[i], half4v); return; }
    i -= Q;
    if (i < Q) { WhUh[i] = __builtin_convertvector(WhU[i], half4v); return; }
    i -= Q;
    if (i < (long)kC * kH / 4) {
      Wch[i] = __builtin_convertvector(Wc[i], half4v);
    } else if (i < (long)kCP * kH / 4) {
      half4v z = {(_Float16)0, (_Float16)0, (_Float16)0, (_Float16)0};
      Wch[i] = z;
    }
    return;
  }
  blk -= 18944;
  if (blk < 2048) {  // x transpose [B,T,F] -> [t*128+b][F], fp16
    int t = blk >> 7, b = blk & 127;
    const flt4v* src = (const flt4v*)(x + ((long)b * kT + t) * kH);
    half4v* dst = (half4v*)(xh + (long)blk * kH);
    dst[threadIdx.x] = __builtin_convertvector(src[threadIdx.x], half4v);
    return;
  }
  blk -= 2048;
  {  // bias packs: br_p/bu_p [j][gate]; bcp padded linear
    int i = blk * 256 + threadIdx.x;
    if (i < kFH) {
      int j = i >> 2, gt = i & 3;
      br_p[i] = biR[gt * kH + j] + bhR[gt * kH + j];
      bu_p[i] = biU[gt * kH + j] + bhU[gt * kH + j];
    }
    if (i < kCP) bcp[i] = (i < kC) ? bc[i] : 0.0f;
  }
}

// ---------------- shared GEMM core: 128x128 tile, K=1024, BK=64, dbuf + swizzle
// LDS per buffer: [128 rows][8 slots of 8 halfs]; slot s holds global k-chunk
// (s ^ (row&7)) -> ds_read_b128 2-way-conflict-free (free per m136).
__device__ __forceinline__ void gemm_k1024(
    const half_t* __restrict__ A, const half_t* __restrict__ B,
    const long* ao, const long* bo, half_t* AsB, half_t* BsB,
    int tid, int wm, int wc, int row16, int g, f32x4 acc[4][4]) {
#pragma unroll
  for (int i = 0; i < 4; ++i) gload16(A + ao[i], AsB + (i * 256 + tid) * 8);
#pragma unroll
  for (int i = 0; i < 4; ++i) gload16(B + bo[i], BsB + (i * 256 + tid) * 8);
  __syncthreads();
  int p = 0;
  for (int kt = 64; kt <= 1024; kt += 64) {
    if (kt < 1024) {
      half_t* as_n = AsB + (p ^ 1) * 8192;
      half_t* bs_n = BsB + (p ^ 1) * 8192;
#pragma unroll
      for (int i = 0; i < 4; ++i) gload16(A + ao[i] + kt, as_n + (i * 256 + tid) * 8);
#pragma unroll
      for (int i = 0; i < 4; ++i) gload16(B + bo[i] + kt, bs_n + (i * 256 + tid) * 8);
    }
    const half_t* as_ = AsB + p * 8192;
    const half_t* bs_ = BsB + p * 8192;
#pragma unroll
    for (int s = 0; s < 2; ++s) {
      half8 af[4], bf[4];
#pragma unroll
      for (int a = 0; a < 4; ++a) {
        const int row = (wm << 6) + (a << 4) + row16;
        const int slot = (s * 4 + g) ^ (row & 7);
        af[a] = *(const half8*)&as_[row * 64 + slot * 8];
      }
#pragma unroll
      for (int b = 0; b < 4; ++b) {
        const int row = (wc << 6) + (b << 4) + row16;
        const int slot = (s * 4 + g) ^ (row & 7);
        bf[b] = *(const half8*)&bs_[row * 64 + slot * 8];
      }
#pragma unroll
      for (int a = 0; a < 4; ++a)
#pragma unroll
        for (int b = 0; b < 4; ++b)
          acc[a][b] = __builtin_amdgcn_mfma_f32_16x16x32_f16(af[a], bf[b], acc[a][b], 0, 0, 0);
    }
    __syncthreads();
    p ^= 1;
  }
}

// gate-interleaved B-row mapping: LDS B-row r -> weight row gate(r)*1024 + j0 + jj(r)
__device__ __forceinline__ int brow_gate(int r, int j0) {
  return (((r >> 4) & 3) << 10) + j0 + ((r >> 6) << 4) + (r & 15);
}

// ---------------- persistent: proj -> 18 pipelined steps -> classifier -------
// Grid = 512 blocks (2/CU forced by 64KiB LDS). block -> (sx = b>>5, jt = b&31).
// Steps separated by manual grid barrier. Segment sx at step u: roll (u<=16,
// sx==0) else chain c. Chains read parity (u&1)^1, write u&1. Roll at u reads
// slot u-2, seeds slot u-1. Finals land in parity-0 slots 0..15 = cls input.
__global__ __launch_bounds__(256, 2) void pipe_persist(
    const half_t* __restrict__ xh,
    const half_t* __restrict__ WiRh, const half_t* __restrict__ WiUh,
    const float* __restrict__ brp, const float* __restrict__ bup,
    const half_t* __restrict__ Wr, const half_t* __restrict__ Wu,
    half_t* __restrict__ xiR, half_t* __restrict__ xiU,
    half_t* __restrict__ Hbuf, float* __restrict__ Cbuf,
    const half_t* __restrict__ Wcw, const float* __restrict__ bcp,
    float* __restrict__ out, unsigned* __restrict__ bar) {
  __shared__ __align__(16) half_t As[2 * 8192];
  __shared__ __align__(16) half_t Bs[2 * 8192];
  unsigned* cnt = bar;
  unsigned* gen = bar + 64;  // separate cachelines
  const int tid = threadIdx.x;
  const int lane = tid & 63;
  const int w = tid >> 6, wm = w >> 1, wc = w & 1;
  const int row16 = lane & 15;
  const int g = lane >> 4;
  const int jt = blockIdx.x & 31;
  const int sx = blockIdx.x >> 5;
  const int j0 = jt << 5;

  // ---- phase 0: input projections (2 tiles per block: z=0 then z=1) ----
#pragma unroll 1
  for (int z = 0; z < 2; ++z) {
    const int tau = blockIdx.x;
    const int m0 = ((tau >> 5) & 15) << 7;
    const int jp0 = (tau & 31) << 5;
    const half_t* Wt = z ? WiUh : WiRh;
    const float* bias_p = z ? bup : brp;
    half_t* xi = z ? xiU : xiR;

    long ao[4], bo[4];
#pragma unroll
    for (int i = 0; i < 4; ++i) {
      const int row = i * 32 + (tid >> 3);
      const int kk = ((tid & 7) ^ (row & 7)) * 8;
      ao[i] = (long)(m0 + row) * kH + kk;
      bo[i] = (long)brow_gate(row, jp0) * kH + kk;
    }
    f32x4 acc[4][4];
    const f32x4 z4 = {0.f, 0.f, 0.f, 0.f};
#pragma unroll
    for (int a = 0; a < 4; ++a)
#pragma unroll
      for (int b = 0; b < 4; ++b) acc[a][b] = z4;
    gemm_k1024(xh, Wt, ao, bo, As, Bs, tid, wm, wc, row16, g, acc);

    const int jg = jp0 + (wc << 4) + row16;
    const f32x4 bv = *(const f32x4*)&bias_p[jg * 4];
#pragma unroll
    for (int a = 0; a < 4; ++a) {
      const int mb = m0 + (wm << 6) + (a << 4) + (g << 2);
#pragma unroll
      for (int r = 0; r < 4; ++r) {
        half4v o;
        o[0] = (half_t)(acc[a][0][r] + bv[0]);
        o[1] = (half_t)(acc[a][1][r] + bv[1]);
        o[2] = (half_t)(acc[a][2][r] + bv[2]);
        o[3] = (half_t)(acc[a][3][r] + bv[3]);
        *(half4v*)&xi[((long)(mb + r) * kH + jg) * 4] = o;
      }
    }
    __syncthreads();
  }
  grid_barrier(cnt, gen);

  // ---- phase 1: 18 pipelined recurrence steps ----
  for (int u = 1; u <= 18; ++u) {
    const int nchain = (u >= 2) ? ((u - 2 < 15 ? u - 2 : 15) + 1) : 0;
    const int nseg = (u <= 16 ? 1 : 0) + nchain;
    if (sx < nseg) {
      const bool isRoll = (u <= 16) && (sx == 0);
      const int c = (u <= 16) ? (sx - 1) : sx;
      const int pr = (u & 1) ^ 1, pw = u & 1;
      const int slot_in_raw = isRoll ? (u - 2) : c;
      const bool zeroA = (slot_in_raw < 0);
      const int slot_in = zeroA ? 0 : slot_in_raw;
      const int slot_out = isRoll ? (u - 1) : c;
      const half_t* A  = Hbuf + (size_t)pr * kPar + (size_t)slot_in * kSlot;
      const float* Cin = Cbuf + (size_t)pr * kPar + (size_t)slot_in * kSlot;
      half_t* Ho = Hbuf + (size_t)pw * kPar + (size_t)slot_out * kSlot;
      float*  Co = Cbuf + (size_t)pw * kPar + (size_t)slot_out * kSlot;
      const half_t* W  = isRoll ? Wr : Wu;
      const half_t* xi = isRoll ? (xiR + (size_t)(u - 1) * 524288)
                                : (xiU + (size_t)c * 524288);

      f32x4 acc[4][4];
      const f32x4 z4 = {0.f, 0.f, 0.f, 0.f};
#pragma unroll
      for (int a = 0; a < 4; ++a)
#pragma unroll
        for (int b = 0; b < 4; ++b) acc[a][b] = z4;

      if (!zeroA) {
        long ao[4], bo[4];
#pragma unroll
        for (int i = 0; i < 4; ++i) {
          const int row = i * 32 + (tid >> 3);
          const int kk = ((tid & 7) ^ (row & 7)) * 8;
          ao[i] = (long)row * kH + kk;
          bo[i] = (long)brow_gate(row, j0) * kH + kk;
        }
        gemm_k1024(A, W, ao, bo, As, Bs, tid, wm, wc, row16, g, acc);
      }

      const int jg = j0 + (wc << 4) + row16;
#pragma unroll
      for (int a = 0; a < 4; ++a) {
        const int mb = (wm << 6) + (a << 4) + (g << 2);
#pragma unroll
        for (int r = 0; r < 4; ++r) {
          const int m = mb + r;
          const half4v xv = *(const half4v*)&xi[((long)m * kH + jg) * 4];
          const float pi = acc[a][0][r] + (float)xv[0];
          const float pf = acc[a][1][r] + (float)xv[1];
          const float pg = acc[a][2][r] + (float)xv[2];
          const float po = acc[a][3][r] + (float)xv[3];
          const float co = zeroA ? 0.0f : Cin[(long)m * kH + jg];
          const float cn = sgm(pf) * co + sgm(pi) * tanhf(pg);
          const float hn = sgm(po) * tanhf(cn);
          Ho[(long)m * kH + jg] = (half_t)hn;
          Co[(long)m * kH + jg] = cn;
        }
      }
      __syncthreads();
    }
    grid_barrier(cnt, gen);
  }

  // ---- phase 2: classifier tail, 320 tiles (t = b/20, n-tile = b%20) ----
  if (blockIdx.x < 320) {
    const int nt = blockIdx.x % 20;
    const int t  = blockIdx.x / 20;
    const int n00 = nt << 7;
    const int m0 = t << 7;

    long ao[4], bo[4];
#pragma unroll
    for (int i = 0; i < 4; ++i) {
      const int row = i * 32 + (tid >> 3);
      const int kk = ((tid & 7) ^ (row & 7)) * 8;
      ao[i] = (long)(m0 + row) * kH + kk;
      bo[i] = (long)(n00 + row) * kH + kk;
    }

    f32x4 acc[4][4];
    const f32x4 z4 = {0.f, 0.f, 0.f, 0.f};
#pragma unroll
    for (int a = 0; a < 4; ++a)
#pragma unroll
      for (int b = 0; b < 4; ++b) acc[a][b] = z4;

    gemm_k1024(Hbuf, Wcw, ao, bo, As, Bs, tid, wm, wc, row16, g, acc);

#pragma unroll
    for (int a = 0; a < 4; ++a) {
      const int mb = m0 + (wm << 6) + (a << 4) + (g << 2);
#pragma unroll
      for (int b = 0; b < 4; ++b) {
        const int n = n00 + (wc << 6) + (b << 4) + row16;
        if (n < kC) {
          const float bvv = bcp[n];
#pragma unroll
          for (int r = 0; r < 4; ++r) {
            const int m = mb + r;
            const int bi = m & 127;
            out[((long)bi * kT + t) * kC + n] = acc[a][b][r] + bvv;
          }
        }
      }
    }
  }
}

extern "C" void kernel_launch(void* const* d_in, const int* in_sizes, int n_in,
                              void* d_out, int out_size, void* d_ws, size_t ws_size,
                              hipStream_t stream) {
  const float* x   = (const float*)d_in[0];
  const float* WiR = (const float*)d_in[1];
  const float* WhR = (const float*)d_in[2];
  const float* biR = (const float*)d_in[3];
  const float* bhR = (const float*)d_in[4];
  const float* WiU = (const float*)d_in[5];
  const float* WhU = (const float*)d_in[6];
  const float* biU = (const float*)d_in[7];
  const float* bhU = (const float*)d_in[8];
  const float* Wc  = (const float*)d_in[9];
  const float* bc  = (const float*)d_in[10];

  size_t off = 0;
  auto alloc = [&](size_t bytes) -> void* {
    void* p = (char*)d_ws + off;
    off += (bytes + 255) & ~(size_t)255;
    return p;
  };
  half_t* xh   = (half_t*)alloc((size_t)2048 * 1024 * 2);
  half_t* WiRh = (half_t*)alloc((size_t)4096 * 1024 * 2);
  half_t* WhRh = (half_t*)alloc((size_t)4096 * 1024 * 2);
  half_t* WiUh = (half_t*)alloc((size_t)4096 * 1024 * 2);
  half_t* WhUh = (half_t*)alloc((size_t)4096 * 1024 * 2);
  half_t* Wch  = (half_t*)alloc((size_t)2560 * 1024 * 2);
  float*  br   = (float*)alloc(4096 * 4);
  float*  bu   = (float*)alloc(4096 * 4);
  float*  bcp  = (float*)alloc(2560 * 4);
  half_t* xiR  = (half_t*)alloc((size_t)2048 * 4096 * 2);
  half_t* xiU  = (half_t*)alloc((size_t)2048 * 4096 * 2);
  half_t* Hbuf = (half_t*)alloc((size_t)2 * kPar * 2);
  float*  Cbuf = (float*)alloc((size_t)2 * kPar * 4);
  unsigned* bar = (unsigned*)alloc(512);
  float*  outp = (float*)d_out;
  (void)ws_size; (void)in_sizes; (void)n_in; (void)out_size;

  // reset barrier state (d_ws is poisoned 0xAA once; must zero every launch)
  hipMemsetAsync(bar, 0, 512, stream);

  // setup: weight casts + x transpose + bias packs (one dispatch)
  setup_all<<<21008, 256, 0, stream>>>(
      (const flt4v*)WiR, (const flt4v*)WhR, (const flt4v*)WiU, (const flt4v*)WhU,
      (const flt4v*)Wc, x, biR, bhR, biU, bhU, bc,
      (half4v*)WiRh, (half4v*)WhRh, (half4v*)WiUh, (half4v*)WhUh, (half4v*)Wch,
      xh, br, bu, bcp);

  // persistent: proj -> pipelined recurrences -> classifier (one dispatch)
  pipe_persist<<<dim3(kBlocks), dim3(256), 0, stream>>>(
      xh, WiRh, WiUh, br, bu, WhRh, WhUh, xiR, xiU, Hbuf, Cbuf, Wch, bcp,
      outp, bar);
}

// Round 6
// 594.000 us; speedup vs baseline: 4.3808x; 4.3808x over previous
//
#include <hip/hip_runtime.h>
#include <cstdint>

using half_t = _Float16;
using half8  = __attribute__((ext_vector_type(8))) _Float16;
using half4v = __attribute__((ext_vector_type(4))) _Float16;
using f32x4  = __attribute__((ext_vector_type(4))) float;
using flt4v  = __attribute__((ext_vector_type(4))) float;

namespace {
constexpr int kT = 16, kH = 1024, kFH = 4096, kC = 2513, kCP = 2560;
constexpr int kSlot = 128 * 1024;   // elements per state slot (128 rows x 1024)
constexpr int kPar  = 17 * kSlot;   // elements per parity plane
}

__device__ __forceinline__ void gload16(const void* g, void* l) {
  __builtin_amdgcn_global_load_lds((const __attribute__((address_space(1))) void*)g,
                                   (__attribute__((address_space(3))) void*)l, 16, 0, 0);
}
__device__ __forceinline__ float sgm(float x) { return 1.0f / (1.0f + __expf(-x)); }

// ---------------- fused setup: weight casts + x transpose + bias packs -------
__global__ void setup_all(const flt4v* __restrict__ WiR, const flt4v* __restrict__ WhR,
                          const flt4v* __restrict__ WiU, const flt4v* __restrict__ WhU,
                          const flt4v* __restrict__ Wc, const float* __restrict__ x,
                          const float* __restrict__ biR, const float* __restrict__ bhR,
                          const float* __restrict__ biU, const float* __restrict__ bhU,
                          const float* __restrict__ bc,
                          half4v* __restrict__ WiRh, half4v* __restrict__ WhRh,
                          half4v* __restrict__ WiUh, half4v* __restrict__ WhUh,
                          half4v* __restrict__ Wch, half_t* __restrict__ xh,
                          float* __restrict__ br_p, float* __restrict__ bu_p,
                          float* __restrict__ bcp) {
  int blk = blockIdx.x;
  if (blk < 18944) {  // weight casts, 1024 f32 elements (256 x flt4v) per block
    long i = (long)blk * 256 + threadIdx.x;
    const long Q = 1048576;
    if (i < Q) { WiRh[i] = __builtin_convertvector(WiR[i], half4v); return; }
    i -= Q;
    if (i < Q) { WhRh[i] = __builtin_convertvector(WhR[i], half4v); return; }
    i -= Q;
    if (i < Q) { WiUh[i] = __builtin_convertvector(WiU[i], half4v); return; }
    i -= Q;
    if (i < Q) { WhUh[i] = __builtin_convertvector(WhU[i], half4v); return; }
    i -= Q;
    if (i < (long)kC * kH / 4) {
      Wch[i] = __builtin_convertvector(Wc[i], half4v);
    } else if (i < (long)kCP * kH / 4) {
      half4v z = {(_Float16)0, (_Float16)0, (_Float16)0, (_Float16)0};
      Wch[i] = z;
    }
    return;
  }
  blk -= 18944;
  if (blk < 2048) {  // x transpose [B,T,F] -> [t*128+b][F], fp16
    int t = blk >> 7, b = blk & 127;
    const flt4v* src = (const flt4v*)(x + ((long)b * kT + t) * kH);
    half4v* dst = (half4v*)(xh + (long)blk * kH);
    dst[threadIdx.x] = __builtin_convertvector(src[threadIdx.x], half4v);
    return;
  }
  blk -= 2048;
  {  // bias packs: br_p/bu_p [j][gate]; bcp padded linear
    int i = blk * 256 + threadIdx.x;
    if (i < kFH) {
      int j = i >> 2, gt = i & 3;
      br_p[i] = biR[gt * kH + j] + bhR[gt * kH + j];
      bu_p[i] = biU[gt * kH + j] + bhU[gt * kH + j];
    }
    if (i < kCP) bcp[i] = (i < kC) ? bc[i] : 0.0f;
  }
}

// gate-interleaved B-row mapping: LDS B-row r -> weight row gate(r)*1024 + j0 + jj(r)
__device__ __forceinline__ int brow_gate(int r, int j0) {
  return (((r >> 4) & 3) << 10) + j0 + ((r >> 6) << 4) + (r & 15);
}

// ---------------- pipelined GEMM core: 128x128 tile, K=1024, BK=32 -----------
// 4 LDS buffers (8KB A + 8KB B each, 64KB total), 3 tiles prefetched ahead,
// counted s_waitcnt vmcnt(8) (T4: never drain to 0 mid-loop), raw s_barrier,
// setprio(1) around the 16-MFMA cluster (T5).
// LDS per buffer: [128 rows][4 slots of 8 halfs]; slot s holds k-chunk
// (s ^ (row&3))*8 -> ds_read_b128 conflict-free (2 lanes/bank).
__device__ __forceinline__ void gemm_pipe(
    const half_t* __restrict__ A, const half_t* __restrict__ B,
    long a0, long a1, long b0, long b1,
    half_t* __restrict__ Ab, half_t* __restrict__ Bb,
    int tid, int wm, int wc, int row16, int g, f32x4 acc[4][4]) {
  auto stage = [&](int t) {
    const int bb = (t & 3) * 4096;
    const long ko = (long)t * 32;
    gload16(A + a0 + ko, Ab + bb + tid * 8);
    gload16(A + a1 + ko, Ab + bb + (256 + tid) * 8);
    gload16(B + b0 + ko, Bb + bb + tid * 8);
    gload16(B + b1 + ko, Bb + bb + (256 + tid) * 8);
  };
  auto barr = [&]() {
    __builtin_amdgcn_sched_barrier(0);
    __builtin_amdgcn_s_barrier();
    __builtin_amdgcn_sched_barrier(0);
  };

  int offA[4], offB[4];
#pragma unroll
  for (int a = 0; a < 4; ++a) {
    const int ra = (wm << 6) + (a << 4) + row16;
    offA[a] = ra * 32 + ((g ^ (ra & 3)) << 3);
    const int rb = (wc << 6) + (a << 4) + row16;
    offB[a] = rb * 32 + ((g ^ (rb & 3)) << 3);
  }

  auto compute = [&](int bi) {
    const half_t* as_ = Ab + bi * 4096;
    const half_t* bs_ = Bb + bi * 4096;
    half8 af[4], bf[4];
#pragma unroll
    for (int a = 0; a < 4; ++a) af[a] = *(const half8*)&as_[offA[a]];
#pragma unroll
    for (int b = 0; b < 4; ++b) bf[b] = *(const half8*)&bs_[offB[b]];
    __builtin_amdgcn_s_setprio(1);
#pragma unroll
    for (int a = 0; a < 4; ++a)
#pragma unroll
      for (int b = 0; b < 4; ++b)
        acc[a][b] = __builtin_amdgcn_mfma_f32_16x16x32_f16(af[a], bf[b], acc[a][b], 0, 0, 0);
    __builtin_amdgcn_s_setprio(0);
  };

  stage(0); stage(1); stage(2);
#pragma unroll 1
  for (int tt = 0; tt < 7; ++tt) {
#pragma unroll
    for (int q = 0; q < 4; ++q) {
      asm volatile("s_waitcnt vmcnt(8)" ::: "memory");
      barr();
      stage(tt * 4 + q + 3);
      compute(q);
    }
  }
  // tail: tiles 28..31 (stages exhausted at 31)
  asm volatile("s_waitcnt vmcnt(8)" ::: "memory"); barr(); stage(31); compute(0);
  asm volatile("s_waitcnt vmcnt(8)" ::: "memory"); barr(); compute(1);
  asm volatile("s_waitcnt vmcnt(4)" ::: "memory"); barr(); compute(2);
  asm volatile("s_waitcnt vmcnt(0)" ::: "memory"); barr(); compute(3);
}

// ---------------- pipelined recurrence step + folded proj segments -----------
// Global step u. Segments sx < nRec: recurrence (roll if u<=16 && sx==0, else
// chain c). Chains read parity (u&1)^1, write u&1. Roll at u reads slot u-2,
// seeds slot u-1. Finals land in parity-0 slots 0..15 (= cls input).
// Segments sx >= nRec: input-projection tiles, proj index p = projBase+(sx-nRec):
//   p=0:(xiR,row0) p=1:(xiU,row0) p in 2..16:(xiR,row p-1) p>=17:(xiU,row p-16)
__global__ __launch_bounds__(256, 2) void pipe_step(
    const int u, const int nRec, const int projBase,
    const half_t* __restrict__ xh,
    const half_t* __restrict__ WiRh, const half_t* __restrict__ WiUh,
    const float* __restrict__ brp, const float* __restrict__ bup,
    const half_t* __restrict__ Wr, const half_t* __restrict__ Wu,
    half_t* __restrict__ xiR, half_t* __restrict__ xiU,
    half_t* __restrict__ Hbuf, float* __restrict__ Cbuf) {
  __shared__ __align__(16) half_t As[4 * 4096];
  __shared__ __align__(16) half_t Bs[4 * 4096];
  const int tid = threadIdx.x;
  const int lane = tid & 63;
  const int w = tid >> 6, wm = w >> 1, wc = w & 1;
  const int row16 = lane & 15;
  const int g = lane >> 4;
  const int jt = blockIdx.x;
  const int j0 = jt << 5;
  const int sx = blockIdx.y;

  const int srow = tid >> 2;                        // staged LDS row (q=0)
  const int kks = ((tid & 3) ^ (srow & 3)) * 8;     // pre-swizzled k-offset

  f32x4 acc[4][4];
  const f32x4 z4 = {0.f, 0.f, 0.f, 0.f};
#pragma unroll
  for (int a = 0; a < 4; ++a)
#pragma unroll
    for (int b = 0; b < 4; ++b) acc[a][b] = z4;

  if (sx < nRec) {
    const bool isRoll = (u <= 16) && (sx == 0);
    const int c = (u <= 16) ? (sx - 1) : sx;
    const int pr = (u & 1) ^ 1, pw = u & 1;
    const int slot_in_raw = isRoll ? (u - 2) : c;
    const bool zeroA = (slot_in_raw < 0);
    const int slot_in = zeroA ? 0 : slot_in_raw;
    const int slot_out = isRoll ? (u - 1) : c;
    const half_t* A  = Hbuf + (size_t)pr * kPar + (size_t)slot_in * kSlot;
    const float* Cin = Cbuf + (size_t)pr * kPar + (size_t)slot_in * kSlot;
    half_t* Ho = Hbuf + (size_t)pw * kPar + (size_t)slot_out * kSlot;
    float*  Co = Cbuf + (size_t)pw * kPar + (size_t)slot_out * kSlot;
    const half_t* W  = isRoll ? Wr : Wu;
    const half_t* xi = isRoll ? (xiR + (size_t)(u - 1) * 524288)
                              : (xiU + (size_t)c * 524288);

    if (!zeroA) {
      const long a0 = (long)srow * kH + kks;
      const long a1 = (long)(srow + 64) * kH + kks;
      const long b0 = (long)brow_gate(srow, j0) * kH + kks;
      const long b1 = (long)brow_gate(srow + 64, j0) * kH + kks;
      gemm_pipe(A, W, a0, a1, b0, b1, As, Bs, tid, wm, wc, row16, g, acc);
    }

    const int jg = j0 + (wc << 4) + row16;
#pragma unroll
    for (int a = 0; a < 4; ++a) {
      const int mb = (wm << 6) + (a << 4) + (g << 2);
#pragma unroll
      for (int r = 0; r < 4; ++r) {
        const int m = mb + r;
        const half4v xv = *(const half4v*)&xi[((long)m * kH + jg) * 4];
        const float pi = acc[a][0][r] + (float)xv[0];
        const float pf = acc[a][1][r] + (float)xv[1];
        const float pg = acc[a][2][r] + (float)xv[2];
        const float po = acc[a][3][r] + (float)xv[3];
        const float co = zeroA ? 0.0f : Cin[(long)m * kH + jg];
        const float cn = sgm(pf) * co + sgm(pi) * tanhf(pg);
        const float hn = sgm(po) * tanhf(cn);
        Ho[(long)m * kH + jg] = (half_t)hn;
        Co[(long)m * kH + jg] = cn;
      }
    }
  } else {
    // ---- folded input-projection tile ----
    const int p = projBase + (sx - nRec);
    int z, r;
    if (p == 0)       { z = 0; r = 0; }
    else if (p == 1)  { z = 1; r = 0; }
    else if (p <= 16) { z = 0; r = p - 1; }
    else              { z = 1; r = p - 16; }
    const half_t* Wt = z ? WiUh : WiRh;
    const float* bias_p = z ? bup : brp;
    half_t* xi = z ? xiU : xiR;
    const int m0 = r << 7;

    const long a0 = (long)(m0 + srow) * kH + kks;
    const long a1 = (long)(m0 + srow + 64) * kH + kks;
    const long b0 = (long)brow_gate(srow, j0) * kH + kks;
    const long b1 = (long)brow_gate(srow + 64, j0) * kH + kks;
    gemm_pipe(xh, Wt, a0, a1, b0, b1, As, Bs, tid, wm, wc, row16, g, acc);

    const int jg = j0 + (wc << 4) + row16;
    const f32x4 bv = *(const f32x4*)&bias_p[jg * 4];
#pragma unroll
    for (int a = 0; a < 4; ++a) {
      const int mb = m0 + (wm << 6) + (a << 4) + (g << 2);
#pragma unroll
      for (int r4 = 0; r4 < 4; ++r4) {
        half4v o;
        o[0] = (half_t)(acc[a][0][r4] + bv[0]);
        o[1] = (half_t)(acc[a][1][r4] + bv[1]);
        o[2] = (half_t)(acc[a][2][r4] + bv[2]);
        o[3] = (half_t)(acc[a][3][r4] + bv[3]);
        *(half4v*)&xi[((long)(mb + r4) * kH + jg) * 4] = o;
      }
    }
  }
}

// ---------------- classifier: A = parity-0 plane of Hbuf ([16][128][1024]) ---
__global__ __launch_bounds__(256, 2) void cls_gemm(
    const half_t* __restrict__ Hfin, const half_t* __restrict__ Wcw,
    const float* __restrict__ bcp, float* __restrict__ out) {
  __shared__ __align__(16) half_t As[4 * 4096];
  __shared__ __align__(16) half_t Bs[4 * 4096];
  const int tid = threadIdx.x;
  const int lane = tid & 63;
  const int w = tid >> 6, wm = w >> 1, wc = w & 1;
  const int row16 = lane & 15;
  const int g = lane >> 4;
  const int n00 = blockIdx.x << 7;
  const int t = blockIdx.y;
  const int m0 = t << 7;

  const int srow = tid >> 2;
  const int kks = ((tid & 3) ^ (srow & 3)) * 8;
  const long a0 = (long)(m0 + srow) * kH + kks;
  const long a1 = (long)(m0 + srow + 64) * kH + kks;
  const long b0 = (long)(n00 + srow) * kH + kks;
  const long b1 = (long)(n00 + srow + 64) * kH + kks;

  f32x4 acc[4][4];
  const f32x4 z4 = {0.f, 0.f, 0.f, 0.f};
#pragma unroll
  for (int a = 0; a < 4; ++a)
#pragma unroll
    for (int b = 0; b < 4; ++b) acc[a][b] = z4;

  gemm_pipe(Hfin, Wcw, a0, a1, b0, b1, As, Bs, tid, wm, wc, row16, g, acc);

#pragma unroll
  for (int a = 0; a < 4; ++a) {
    const int mb = m0 + (wm << 6) + (a << 4) + (g << 2);
#pragma unroll
    for (int b = 0; b < 4; ++b) {
      const int n = n00 + (wc << 6) + (b << 4) + row16;
      if (n < kC) {
        const float bvv = bcp[n];
#pragma unroll
        for (int r = 0; r < 4; ++r) {
          const int m = mb + r;
          const int bi = m & 127;
          out[((long)bi * kT + t) * kC + n] = acc[a][b][r] + bvv;
        }
      }
    }
  }
}

extern "C" void kernel_launch(void* const* d_in, const int* in_sizes, int n_in,
                              void* d_out, int out_size, void* d_ws, size_t ws_size,
                              hipStream_t stream) {
  const float* x   = (const float*)d_in[0];
  const float* WiR = (const float*)d_in[1];
  const float* WhR = (const float*)d_in[2];
  const float* biR = (const float*)d_in[3];
  const float* bhR = (const float*)d_in[4];
  const float* WiU = (const float*)d_in[5];
  const float* WhU = (const float*)d_in[6];
  const float* biU = (const float*)d_in[7];
  const float* bhU = (const float*)d_in[8];
  const float* Wc  = (const float*)d_in[9];
  const float* bc  = (const float*)d_in[10];

  size_t off = 0;
  auto alloc = [&](size_t bytes) -> void* {
    void* p = (char*)d_ws + off;
    off += (bytes + 255) & ~(size_t)255;
    return p;
  };
  half_t* xh   = (half_t*)alloc((size_t)2048 * 1024 * 2);
  half_t* WiRh = (half_t*)alloc((size_t)4096 * 1024 * 2);
  half_t* WhRh = (half_t*)alloc((size_t)4096 * 1024 * 2);
  half_t* WiUh = (half_t*)alloc((size_t)4096 * 1024 * 2);
  half_t* WhUh = (half_t*)alloc((size_t)4096 * 1024 * 2);
  half_t* Wch  = (half_t*)alloc((size_t)2560 * 1024 * 2);
  float*  br   = (float*)alloc(4096 * 4);
  float*  bu   = (float*)alloc(4096 * 4);
  float*  bcp  = (float*)alloc(2560 * 4);
  half_t* xiR  = (half_t*)alloc((size_t)2048 * 4096 * 2);
  half_t* xiU  = (half_t*)alloc((size_t)2048 * 4096 * 2);
  half_t* Hbuf = (half_t*)alloc((size_t)2 * kPar * 2);
  float*  Cbuf = (float*)alloc((size_t)2 * kPar * 4);
  float*  outp = (float*)d_out;
  (void)ws_size; (void)in_sizes; (void)n_in; (void)out_size;

  // setup: weight casts + x transpose + bias packs (one dispatch)
  setup_all<<<21008, 256, 0, stream>>>(
      (const flt4v*)WiR, (const flt4v*)WhR, (const flt4v*)WiU, (const flt4v*)WhU,
      (const flt4v*)Wc, x, biR, bhR, biU, bhU, bc,
      (half4v*)WiRh, (half4v*)WhRh, (half4v*)WiUh, (half4v*)WhUh, (half4v*)Wch,
      xh, br, bu, bcp);

  // P0: proj p=0..2 (xiR r0, xiU r0, xiR r1) — seeds for u=1,2
  pipe_step<<<dim3(32, 3), 256, 0, stream>>>(0, 0, 0, xh, WiRh, WiUh, br, bu,
                                             WhRh, WhUh, xiR, xiU, Hbuf, Cbuf);

  // pipelined recurrences (proj tiles folded into the idle early steps)
  for (int u = 1; u <= 18; ++u) {
    const int nchain = (u >= 2) ? ((u - 2 < 15 ? u - 2 : 15) + 1) : 0;
    const int nRec = (u <= 16 ? 1 : 0) + nchain;
    int projBase = 0, nProj = 0;
    if (u == 1) { projBase = 3;  nProj = 14; }   // xiR rows 2..15
    if (u == 2) { projBase = 17; nProj = 14; }   // xiU rows 1..14
    if (u == 3) { projBase = 31; nProj = 1;  }   // xiU row 15
    pipe_step<<<dim3(32, nRec + nProj), 256, 0, stream>>>(
        u, nRec, projBase, xh, WiRh, WiUh, br, bu, WhRh, WhUh, xiR, xiU,
        Hbuf, Cbuf);
  }

  // classifier: finals are parity-0 slots 0..15 = [16][128][1024] contiguous
  cls_gemm<<<dim3(20, 16), 256, 0, stream>>>(Hbuf, Wch, bcp, (float*)outp);
}

// Round 7
// 501.888 us; speedup vs baseline: 5.1848x; 1.1835x over previous
//
#include <hip/hip_runtime.h>
#include <cstdint>

using half_t = _Float16;
using half8  = __attribute__((ext_vector_type(8))) _Float16;
using half4v = __attribute__((ext_vector_type(4))) _Float16;
using f32x4  = __attribute__((ext_vector_type(4))) float;
using flt4v  = __attribute__((ext_vector_type(4))) float;

namespace {
constexpr int kT = 16, kH = 1024, kFH = 4096, kC = 2513, kCP = 2560;
constexpr int kSlot = 128 * 1024;   // elements per state slot (128 rows x 1024)
constexpr int kPar  = 17 * kSlot;   // elements per parity plane
}

__device__ __forceinline__ void gload16(const void* g, void* l) {
  __builtin_amdgcn_global_load_lds((const __attribute__((address_space(1))) void*)g,
                                   (__attribute__((address_space(3))) void*)l, 16, 0, 0);
}
__device__ __forceinline__ float sgm(float x) { return 1.0f / (1.0f + __expf(-x)); }

// ---------------- fused setup: weight casts + x transpose + bias packs -------
__global__ void setup_all(const flt4v* __restrict__ WiR, const flt4v* __restrict__ WhR,
                          const flt4v* __restrict__ WiU, const flt4v* __restrict__ WhU,
                          const flt4v* __restrict__ Wc, const float* __restrict__ x,
                          const float* __restrict__ biR, const float* __restrict__ bhR,
                          const float* __restrict__ biU, const float* __restrict__ bhU,
                          const float* __restrict__ bc,
                          half4v* __restrict__ WiRh, half4v* __restrict__ WhRh,
                          half4v* __restrict__ WiUh, half4v* __restrict__ WhUh,
                          half4v* __restrict__ Wch, half_t* __restrict__ xh,
                          float* __restrict__ br_p, float* __restrict__ bu_p,
                          float* __restrict__ bcp) {
  int blk = blockIdx.x;
  if (blk < 18944) {  // weight casts, 1024 f32 elements (256 x flt4v) per block
    long i = (long)blk * 256 + threadIdx.x;
    const long Q = 1048576;
    if (i < Q) { WiRh[i] = __builtin_convertvector(WiR[i], half4v); return; }
    i -= Q;
    if (i < Q) { WhRh[i] = __builtin_convertvector(WhR[i], half4v); return; }
    i -= Q;
    if (i < Q) { WiUh[i] = __builtin_convertvector(WiU[i], half4v); return; }
    i -= Q;
    if (i < Q) { WhUh[i] = __builtin_convertvector(WhU[i], half4v); return; }
    i -= Q;
    if (i < (long)kC * kH / 4) {
      Wch[i] = __builtin_convertvector(Wc[i], half4v);
    } else if (i < (long)kCP * kH / 4) {
      half4v z = {(_Float16)0, (_Float16)0, (_Float16)0, (_Float16)0};
      Wch[i] = z;
    }
    return;
  }
  blk -= 18944;
  if (blk < 2048) {  // x transpose [B,T,F] -> [t*128+b][F], fp16
    int t = blk >> 7, b = blk & 127;
    const flt4v* src = (const flt4v*)(x + ((long)b * kT + t) * kH);
    half4v* dst = (half4v*)(xh + (long)blk * kH);
    dst[threadIdx.x] = __builtin_convertvector(src[threadIdx.x], half4v);
    return;
  }
  blk -= 2048;
  {  // bias packs: br_p/bu_p [j][gate]; bcp padded linear
    int i = blk * 256 + threadIdx.x;
    if (i < kFH) {
      int j = i >> 2, gt = i & 3;
      br_p[i] = biR[gt * kH + j] + bhR[gt * kH + j];
      bu_p[i] = biU[gt * kH + j] + bhU[gt * kH + j];
    }
    if (i < kCP) bcp[i] = (i < kC) ? bc[i] : 0.0f;
  }
}

// gate-interleaved B-row mapping: LDS B-row r -> weight row gate(r)*1024 + j0 + jj(r)
__device__ __forceinline__ int brow_gate(int r, int j0) {
  return (((r >> 4) & 3) << 10) + j0 + ((r >> 6) << 4) + (r & 15);
}

// ---------------- GEMM core: MR x 128 tile, K=1024, BK=64, dbuf + swizzle ----
// (round-3 proven core, templated on M rows: 128 = full, 64 = half-tile.)
// LDS per buffer: [MR rows][8 slots of 8 halfs]; slot s holds global k-chunk
// (s ^ (row&7)) -> ds_read_b128 2-way-conflict-free (free per m136).
template <int MR>
__device__ __forceinline__ void gemm_core(
    const half_t* __restrict__ A, const half_t* __restrict__ B,
    const long* ao, const long* bo, half_t* AsB, half_t* BsB,
    int tid, int wm, int wc, int row16, int g, f32x4 acc[][4]) {
  constexpr int UA = MR / 32;       // A stage iterations per thread
  constexpr int ABUF = MR * 64;     // halfs per A buffer
#pragma unroll
  for (int i = 0; i < UA; ++i) gload16(A + ao[i], AsB + (i * 256 + tid) * 8);
#pragma unroll
  for (int i = 0; i < 4; ++i) gload16(B + bo[i], BsB + (i * 256 + tid) * 8);
  __syncthreads();
  int p = 0;
  for (int kt = 64; kt <= 1024; kt += 64) {
    if (kt < 1024) {
      half_t* as_n = AsB + (p ^ 1) * ABUF;
      half_t* bs_n = BsB + (p ^ 1) * 8192;
#pragma unroll
      for (int i = 0; i < UA; ++i) gload16(A + ao[i] + kt, as_n + (i * 256 + tid) * 8);
#pragma unroll
      for (int i = 0; i < 4; ++i) gload16(B + bo[i] + kt, bs_n + (i * 256 + tid) * 8);
    }
    const half_t* as_ = AsB + p * ABUF;
    const half_t* bs_ = BsB + p * 8192;
#pragma unroll
    for (int s = 0; s < 2; ++s) {
      half8 af[UA], bf[4];
#pragma unroll
      for (int a = 0; a < UA; ++a) {
        const int row = wm * (MR / 2) + (a << 4) + row16;
        const int slot = (s * 4 + g) ^ (row & 7);
        af[a] = *(const half8*)&as_[row * 64 + slot * 8];
      }
#pragma unroll
      for (int b = 0; b < 4; ++b) {
        const int row = (wc << 6) + (b << 4) + row16;
        const int slot = (s * 4 + g) ^ (row & 7);
        bf[b] = *(const half8*)&bs_[row * 64 + slot * 8];
      }
#pragma unroll
      for (int a = 0; a < UA; ++a)
#pragma unroll
        for (int b = 0; b < 4; ++b)
          acc[a][b] = __builtin_amdgcn_mfma_f32_16x16x32_f16(af[a], bf[b], acc[a][b], 0, 0, 0);
    }
    __syncthreads();
    p ^= 1;
  }
}

// ---------------- pipelined recurrence step + folded proj segments -----------
// Global step u. MR=64: blockIdx.y = 2*seg + mhalf; MR=128: blockIdx.y = seg.
// Segments seg < nRec: recurrence (roll if u<=16 && seg==0, else chain c).
// Chains read parity (u&1)^1, write u&1. Roll at u reads slot u-2, seeds slot
// u-1. Finals land in parity-0 slots 0..15 (= cls input).
// Segments seg >= nRec: proj tiles, p = projBase + (seg - nRec):
//   p=0:(xiR,r0) p=1:(xiU,r0) p in 2..16:(xiR,r p-1) p>=17:(xiU,r p-16)
template <int MR>
__global__ __launch_bounds__(256, (MR == 64 ? 3 : 2)) void pipe_step(
    const int u, const int nRec, const int projBase,
    const half_t* __restrict__ xh,
    const half_t* __restrict__ WiRh, const half_t* __restrict__ WiUh,
    const float* __restrict__ brp, const float* __restrict__ bup,
    const half_t* __restrict__ Wr, const half_t* __restrict__ Wu,
    half_t* __restrict__ xiR, half_t* __restrict__ xiU,
    half_t* __restrict__ Hbuf, float* __restrict__ Cbuf) {
  __shared__ __align__(16) half_t As[2 * MR * 64];
  __shared__ __align__(16) half_t Bs[2 * 8192];
  constexpr int FA = MR / 32;       // A fragments per wave
  const int tid = threadIdx.x;
  const int lane = tid & 63;
  const int w = tid >> 6, wm = w >> 1, wc = w & 1;
  const int row16 = lane & 15;
  const int g = lane >> 4;
  const int j0 = blockIdx.x << 5;   // j-tile; XCD = blockIdx.x%8 (32*y % 8 == 0)
  const int sy = blockIdx.y;
  const int seg = (MR == 64) ? (sy >> 1) : sy;
  const int mrow0 = (MR == 64) ? ((sy & 1) << 6) : 0;

  f32x4 acc[FA][4];
  const f32x4 z4 = {0.f, 0.f, 0.f, 0.f};
#pragma unroll
  for (int a = 0; a < FA; ++a)
#pragma unroll
    for (int b = 0; b < 4; ++b) acc[a][b] = z4;

  // staging rows/offsets (LDS-local row; kk pre-swizzled k-offset)
  int srow[4], skk[4];
#pragma unroll
  for (int i = 0; i < 4; ++i) {
    srow[i] = i * 32 + (tid >> 3);
    skk[i] = ((tid & 7) ^ (srow[i] & 7)) * 8;
  }

  if (seg < nRec) {
    const bool isRoll = (u <= 16) && (seg == 0);
    const int c = (u <= 16) ? (seg - 1) : seg;
    const int pr = (u & 1) ^ 1, pw = u & 1;
    const int slot_in_raw = isRoll ? (u - 2) : c;
    const bool zeroA = (slot_in_raw < 0);
    const int slot_in = zeroA ? 0 : slot_in_raw;
    const int slot_out = isRoll ? (u - 1) : c;
    const half_t* A  = Hbuf + (size_t)pr * kPar + (size_t)slot_in * kSlot;
    const float* Cin = Cbuf + (size_t)pr * kPar + (size_t)slot_in * kSlot;
    half_t* Ho = Hbuf + (size_t)pw * kPar + (size_t)slot_out * kSlot;
    float*  Co = Cbuf + (size_t)pw * kPar + (size_t)slot_out * kSlot;
    const half_t* W  = isRoll ? Wr : Wu;
    const half_t* xi = isRoll ? (xiR + (size_t)(u - 1) * 524288)
                              : (xiU + (size_t)c * 524288);

    if (!zeroA) {
      long ao[FA], bo[4];
#pragma unroll
      for (int i = 0; i < FA; ++i) ao[i] = (long)(mrow0 + srow[i]) * kH + skk[i];
#pragma unroll
      for (int i = 0; i < 4; ++i) bo[i] = (long)brow_gate(srow[i], j0) * kH + skk[i];
      gemm_core<MR>(A, W, ao, bo, As, Bs, tid, wm, wc, row16, g, acc);
    }

    const int jg = j0 + (wc << 4) + row16;
#pragma unroll
    for (int a = 0; a < FA; ++a) {
      const int mb = mrow0 + wm * (MR / 2) + (a << 4) + (g << 2);
#pragma unroll
      for (int r = 0; r < 4; ++r) {
        const int m = mb + r;
        const half4v xv = *(const half4v*)&xi[((long)m * kH + jg) * 4];
        const float pi = acc[a][0][r] + (float)xv[0];
        const float pf = acc[a][1][r] + (float)xv[1];
        const float pg = acc[a][2][r] + (float)xv[2];
        const float po = acc[a][3][r] + (float)xv[3];
        const float co = zeroA ? 0.0f : Cin[(long)m * kH + jg];
        const float cn = sgm(pf) * co + sgm(pi) * tanhf(pg);
        const float hn = sgm(po) * tanhf(cn);
        Ho[(long)m * kH + jg] = (half_t)hn;
        Co[(long)m * kH + jg] = cn;
      }
    }
  } else {
    // ---- folded input-projection tile ----
    const int p = projBase + (seg - nRec);
    int z, rr;
    if (p == 0)       { z = 0; rr = 0; }
    else if (p == 1)  { z = 1; rr = 0; }
    else if (p <= 16) { z = 0; rr = p - 1; }
    else              { z = 1; rr = p - 16; }
    const half_t* Wt = z ? WiUh : WiRh;
    const float* bias_p = z ? bup : brp;
    half_t* xi = z ? xiU : xiR;
    const int m0 = (rr << 7) + mrow0;

    long ao[FA], bo[4];
#pragma unroll
    for (int i = 0; i < FA; ++i) ao[i] = (long)(m0 + srow[i]) * kH + skk[i];
#pragma unroll
    for (int i = 0; i < 4; ++i) bo[i] = (long)brow_gate(srow[i], j0) * kH + skk[i];
    gemm_core<MR>(xh, Wt, ao, bo, As, Bs, tid, wm, wc, row16, g, acc);

    const int jg = j0 + (wc << 4) + row16;
    const f32x4 bv = *(const f32x4*)&bias_p[jg * 4];
#pragma unroll
    for (int a = 0; a < FA; ++a) {
      const int mb = m0 + wm * (MR / 2) + (a << 4) + (g << 2);
#pragma unroll
      for (int r4 = 0; r4 < 4; ++r4) {
        half4v o;
        o[0] = (half_t)(acc[a][0][r4] + bv[0]);
        o[1] = (half_t)(acc[a][1][r4] + bv[1]);
        o[2] = (half_t)(acc[a][2][r4] + bv[2]);
        o[3] = (half_t)(acc[a][3][r4] + bv[3]);
        *(half4v*)&xi[((long)(mb + r4) * kH + jg) * 4] = o;
      }
    }
  }
}

// ---------------- classifier: half-tiles; A = parity-0 plane of Hbuf ---------
__global__ __launch_bounds__(256, 3) void cls_gemm(
    const half_t* __restrict__ Hfin, const half_t* __restrict__ Wcw,
    const float* __restrict__ bcp, float* __restrict__ out) {
  __shared__ __align__(16) half_t As[2 * 4096];
  __shared__ __align__(16) half_t Bs[2 * 8192];
  const int tid = threadIdx.x;
  const int lane = tid & 63;
  const int w = tid >> 6, wm = w >> 1, wc = w & 1;
  const int row16 = lane & 15;
  const int g = lane >> 4;
  const int n00 = blockIdx.x << 7;
  const int t = blockIdx.y >> 1;
  const int m0 = (t << 7) + ((blockIdx.y & 1) << 6);

  int srow[4], skk[4];
#pragma unroll
  for (int i = 0; i < 4; ++i) {
    srow[i] = i * 32 + (tid >> 3);
    skk[i] = ((tid & 7) ^ (srow[i] & 7)) * 8;
  }
  long ao[2], bo[4];
#pragma unroll
  for (int i = 0; i < 2; ++i) ao[i] = (long)(m0 + srow[i]) * kH + skk[i];
#pragma unroll
  for (int i = 0; i < 4; ++i) bo[i] = (long)(n00 + srow[i]) * kH + skk[i];

  f32x4 acc[2][4];
  const f32x4 z4 = {0.f, 0.f, 0.f, 0.f};
#pragma unroll
  for (int a = 0; a < 2; ++a)
#pragma unroll
    for (int b = 0; b < 4; ++b) acc[a][b] = z4;

  gemm_core<64>(Hfin, Wcw, ao, bo, As, Bs, tid, wm, wc, row16, g, acc);

#pragma unroll
  for (int a = 0; a < 2; ++a) {
    const int mb = m0 + wm * 32 + (a << 4) + (g << 2);
#pragma unroll
    for (int b = 0; b < 4; ++b) {
      const int n = n00 + (wc << 6) + (b << 4) + row16;
      if (n < kC) {
        const float bvv = bcp[n];
#pragma unroll
        for (int r = 0; r < 4; ++r) {
          const int m = mb + r;
          const int bi = m & 127;
          out[((long)bi * kT + t) * kC + n] = acc[a][b][r] + bvv;
        }
      }
    }
  }
}

extern "C" void kernel_launch(void* const* d_in, const int* in_sizes, int n_in,
                              void* d_out, int out_size, void* d_ws, size_t ws_size,
                              hipStream_t stream) {
  const float* x   = (const float*)d_in[0];
  const float* WiR = (const float*)d_in[1];
  const float* WhR = (const float*)d_in[2];
  const float* biR = (const float*)d_in[3];
  const float* bhR = (const float*)d_in[4];
  const float* WiU = (const float*)d_in[5];
  const float* WhU = (const float*)d_in[6];
  const float* biU = (const float*)d_in[7];
  const float* bhU = (const float*)d_in[8];
  const float* Wc  = (const float*)d_in[9];
  const float* bc  = (const float*)d_in[10];

  size_t off = 0;
  auto alloc = [&](size_t bytes) -> void* {
    void* p = (char*)d_ws + off;
    off += (bytes + 255) & ~(size_t)255;
    return p;
  };
  half_t* xh   = (half_t*)alloc((size_t)2048 * 1024 * 2);
  half_t* WiRh = (half_t*)alloc((size_t)4096 * 1024 * 2);
  half_t* WhRh = (half_t*)alloc((size_t)4096 * 1024 * 2);
  half_t* WiUh = (half_t*)alloc((size_t)4096 * 1024 * 2);
  half_t* WhUh = (half_t*)alloc((size_t)4096 * 1024 * 2);
  half_t* Wch  = (half_t*)alloc((size_t)2560 * 1024 * 2);
  float*  br   = (float*)alloc(4096 * 4);
  float*  bu   = (float*)alloc(4096 * 4);
  float*  bcp  = (float*)alloc(2560 * 4);
  half_t* xiR  = (half_t*)alloc((size_t)2048 * 4096 * 2);
  half_t* xiU  = (half_t*)alloc((size_t)2048 * 4096 * 2);
  half_t* Hbuf = (half_t*)alloc((size_t)2 * kPar * 2);
  float*  Cbuf = (float*)alloc((size_t)2 * kPar * 4);
  float*  outp = (float*)d_out;
  (void)ws_size; (void)in_sizes; (void)n_in; (void)out_size;

  // setup: weight casts + x transpose + bias packs (one dispatch)
  setup_all<<<21008, 256, 0, stream>>>(
      (const flt4v*)WiR, (const flt4v*)WhR, (const flt4v*)WiU, (const flt4v*)WhU,
      (const flt4v*)Wc, x, biR, bhR, biU, bhU, bc,
      (half4v*)WiRh, (half4v*)WhRh, (half4v*)WiUh, (half4v*)WhUh, (half4v*)Wch,
      xh, br, bu, bcp);

  // P0: proj p=0..2 (xiR r0, xiU r0, xiR r1) as 6 half-tiles — seeds u=1,2
  pipe_step<64><<<dim3(32, 6), 256, 0, stream>>>(
      0, 0, 0, xh, WiRh, WiUh, br, bu, WhRh, WhUh, xiR, xiU, Hbuf, Cbuf);

  // pipelined recurrences; proj folded into early steps (cap 12 full segs):
  //  u=1: p=3..13 (xiR r2..12), u=2: p=14..23 (xiR r13..15 + xiU r1..7),
  //  u=3: p=24..31 (xiU r8..15). All deps land >=1 dispatch before first read.
  for (int u = 1; u <= 18; ++u) {
    const int nchain = (u >= 2) ? ((u - 2 < 15 ? u - 2 : 15) + 1) : 0;
    const int nRec = (u <= 16 ? 1 : 0) + nchain;
    int projBase = 0, nProj = 0;
    if (u == 1) { projBase = 3;  nProj = 11; }
    if (u == 2) { projBase = 14; nProj = 10; }
    if (u == 3) { projBase = 24; nProj = 8;  }
    if (u <= 12) {
      pipe_step<64><<<dim3(32, 2 * (nRec + nProj)), 256, 0, stream>>>(
          u, nRec, projBase, xh, WiRh, WiUh, br, bu, WhRh, WhUh, xiR, xiU,
          Hbuf, Cbuf);
    } else {
      pipe_step<128><<<dim3(32, nRec), 256, 0, stream>>>(
          u, nRec, 0, xh, WiRh, WiUh, br, bu, WhRh, WhUh, xiR, xiU,
          Hbuf, Cbuf);
    }
  }

  // classifier: finals are parity-0 slots 0..15; half-tiles (20 x 32 grid)
  cls_gemm<<<dim3(20, 32), 256, 0, stream>>>(Hbuf, Wch, bcp, (float*)outp);
}